// Round 2
// baseline (1485.053 us; speedup 1.0000x reference)
//
#include <hip/hip_runtime.h>
#include <hip/hip_bf16.h>

#define N_NODES 50000
#define N_EDGES 800000
#define D 128

// ---------------------------------------------------------------------------
// ws layout:  [0, D*D*4) = W^T (fp32)    -- only 64 KB of ws used
// d_out doubles as the agg accumulator: zeroed, scattered into, then
// transformed in place by the GEMM (row-owning lanes live in one wave;
// loads complete before stores in program order, pointers alias so the
// compiler cannot reorder across them).
// ---------------------------------------------------------------------------

__global__ void zero_out(float4* __restrict__ p, int n4) {
    int i = blockIdx.x * 256 + threadIdx.x;
    if (i < n4) p[i] = make_float4(0.f, 0.f, 0.f, 0.f);
}

// W[out][in] -> Wt[in][out]
__global__ void transpose_w(const float* __restrict__ W, float* __restrict__ Wt) {
    int i = blockIdx.x * 256 + threadIdx.x;   // 16384 total
    if (i >= D * D) return;
    int k = i >> 7;        // in
    int o = i & 127;       // out
    Wt[i] = W[o * D + k];
}

// One thread per (edge, 4-float chunk): 800000 * 32 threads.
// NOTE: harness delivers integer inputs as int32.
__global__ void scatter_edges(const float* __restrict__ x,
                              const int* __restrict__ src,
                              const int* __restrict__ dst,
                              float* __restrict__ agg) {
    long long tid = (long long)blockIdx.x * 256 + threadIdx.x;
    if (tid >= (long long)N_EDGES * 32) return;
    int edge = (int)(tid >> 5);
    int c    = ((int)tid & 31) << 2;   // float offset in row, 0..124
    int s = src[edge];
    int d = dst[edge];
    const float4 v = *(const float4*)(x + (size_t)s * D + c);
    float* p = agg + (size_t)d * D + c;
    unsafeAtomicAdd(p + 0, v.x);
    unsafeAtomicAdd(p + 1, v.y);
    unsafeAtomicAdd(p + 2, v.z);
    unsafeAtomicAdd(p + 3, v.w);
}

// In place: data[n][o] = relu(sum_k data[n][k] * Wt[k][o]) + x[n][o]
// Block: 256 threads. tx covers all 128 outs (o4 = tx*4); each (ty, i)
// owns one node row; all 32 lanes of a row are in the same wave.
__global__ void __launch_bounds__(256)
gemm_relu_res(float* data,                      // agg in, out out (aliases!)
              const float* __restrict__ Wt,
              const float* __restrict__ x) {
    const int tx = threadIdx.x & 31;
    const int ty = threadIdx.x >> 5;
    const int o4 = tx << 2;
    const int n_base = blockIdx.x * 32 + ty * 4;

    float4 acc[4];
    acc[0] = acc[1] = acc[2] = acc[3] = make_float4(0.f, 0.f, 0.f, 0.f);

    const bool ok[4] = { n_base + 0 < N_NODES, n_base + 1 < N_NODES,
                         n_base + 2 < N_NODES, n_base + 3 < N_NODES };

    for (int k = 0; k < D; k += 4) {
        float4 w0 = *(const float4*)(Wt + (k + 0) * D + o4);
        float4 w1 = *(const float4*)(Wt + (k + 1) * D + o4);
        float4 w2 = *(const float4*)(Wt + (k + 2) * D + o4);
        float4 w3 = *(const float4*)(Wt + (k + 3) * D + o4);
#pragma unroll
        for (int i = 0; i < 4; ++i) {
            if (!ok[i]) continue;
            float4 a = *(const float4*)(data + (size_t)(n_base + i) * D + k);
            acc[i].x += a.x * w0.x + a.y * w1.x + a.z * w2.x + a.w * w3.x;
            acc[i].y += a.x * w0.y + a.y * w1.y + a.z * w2.y + a.w * w3.y;
            acc[i].z += a.x * w0.z + a.y * w1.z + a.z * w2.z + a.w * w3.z;
            acc[i].w += a.x * w0.w + a.y * w1.w + a.z * w2.w + a.w * w3.w;
        }
    }

#pragma unroll
    for (int i = 0; i < 4; ++i) {
        if (!ok[i]) continue;
        float4 xi = *(const float4*)(x + (size_t)(n_base + i) * D + o4);
        float4 r;
        r.x = fmaxf(acc[i].x, 0.f) + xi.x;
        r.y = fmaxf(acc[i].y, 0.f) + xi.y;
        r.z = fmaxf(acc[i].z, 0.f) + xi.z;
        r.w = fmaxf(acc[i].w, 0.f) + xi.w;
        *(float4*)(data + (size_t)(n_base + i) * D + o4) = r;
    }
}

extern "C" void kernel_launch(void* const* d_in, const int* in_sizes, int n_in,
                              void* d_out, int out_size, void* d_ws, size_t ws_size,
                              hipStream_t stream) {
    const float* x   = (const float*)d_in[0];
    const int*   src = (const int*)d_in[1];   // harness passes integers as int32
    const int*   dst = (const int*)d_in[2];
    const float* W   = (const float*)d_in[3];
    float* out = (float*)d_out;
    float* Wt  = (float*)d_ws;

    // zero d_out (it is poisoned 0xAA before each call), it serves as agg
    int n4 = N_NODES * D / 4;   // 1.6M float4
    zero_out<<<(n4 + 255) / 256, 256, 0, stream>>>((float4*)out, n4);

    transpose_w<<<(D * D + 255) / 256, 256, 0, stream>>>(W, Wt);

    long long n_scatter = (long long)N_EDGES * 32;
    int blocks_scatter = (int)((n_scatter + 255) / 256);
    scatter_edges<<<blocks_scatter, 256, 0, stream>>>(x, src, dst, out);

    int blocks_gemm = (N_NODES + 31) / 32;  // 1563
    gemm_relu_res<<<blocks_gemm, 256, 0, stream>>>(out, Wt, x);
}

// Round 3
// 365.710 us; speedup vs baseline: 4.0607x; 4.0607x over previous
//
#include <hip/hip_runtime.h>
#include <hip/hip_bf16.h>

#define N_NODES 50000
#define N_EDGES 800000
#define D 128

// ---------------------------------------------------------------------------
// ws layout (all 4-byte elements, ~3.9 MB total):
//   Wt         : D*D floats          (64 KB)
//   cnt        : N_NODES ints        (200 KB)
//   off        : N_NODES+1 ints      (200 KB)
//   cursor     : N_NODES ints        (200 KB)
//   sorted_src : N_EDGES ints        (3.2 MB)
// d_out doubles as agg accumulator (gather-sum writes it, GEMM transforms
// it in place — all lanes owning a row are in one wave, loads precede
// stores in program order and pointers alias, so no reorder hazard).
// ---------------------------------------------------------------------------

__global__ void init_ws(int* __restrict__ cnt, int* __restrict__ cursor,
                        const float* __restrict__ W, float* __restrict__ Wt) {
    int i = blockIdx.x * 256 + threadIdx.x;
    if (i < N_NODES) { cnt[i] = 0; cursor[i] = 0; }
    if (i < D * D)   Wt[i] = W[(i & 127) * D + (i >> 7)];   // Wt[k][o] = W[o][k]
}

__global__ void histogram(const int* __restrict__ dst, int* __restrict__ cnt) {
    int e = blockIdx.x * 256 + threadIdx.x;
    if (e >= N_EDGES) return;
    atomicAdd(&cnt[dst[e]], 1);
}

#define SCAN_THREADS 1024
__global__ void __launch_bounds__(SCAN_THREADS)
scan_counts(const int* __restrict__ cnt, int* __restrict__ off) {
    __shared__ int partial[SCAN_THREADS];
    const int t = threadIdx.x;
    const int CHUNK = (N_NODES + SCAN_THREADS - 1) / SCAN_THREADS;  // 49
    const int base = t * CHUNK;
    int sum = 0;
    for (int i = 0; i < CHUNK; ++i) {
        int idx = base + i;
        if (idx < N_NODES) sum += cnt[idx];
    }
    partial[t] = sum;
    __syncthreads();
    for (int ofs = 1; ofs < SCAN_THREADS; ofs <<= 1) {
        int v = (t >= ofs) ? partial[t - ofs] : 0;
        __syncthreads();
        partial[t] += v;
        __syncthreads();
    }
    int run = (t == 0) ? 0 : partial[t - 1];
    for (int i = 0; i < CHUNK; ++i) {
        int idx = base + i;
        if (idx < N_NODES) { off[idx] = run; run += cnt[idx]; }
    }
    if (t == SCAN_THREADS - 1) off[N_NODES] = run;
}

__global__ void build_sorted(const int* __restrict__ src, const int* __restrict__ dst,
                             const int* __restrict__ off, int* __restrict__ cursor,
                             int* __restrict__ sorted_src) {
    int e = blockIdx.x * 256 + threadIdx.x;
    if (e >= N_EDGES) return;
    int d = dst[e];
    int p = off[d] + atomicAdd(&cursor[d], 1);
    sorted_src[p] = src[e];
}

// One wave per node: 64 lanes x float2 covers the 128-float row.
__global__ void __launch_bounds__(256)
gather_sum(const float* __restrict__ x,
           const int* __restrict__ sorted_src,
           const int* __restrict__ off,
           float* __restrict__ agg) {
    int wave = (int)((blockIdx.x * 256 + threadIdx.x) >> 6);
    int lane = threadIdx.x & 63;
    if (wave >= N_NODES) return;
    int beg = off[wave], end = off[wave + 1];
    const int c = lane * 2;
    float2 acc = make_float2(0.f, 0.f);
    int e = beg;
    // 2-deep unroll for a little MLP on the row gathers
    for (; e + 1 < end; e += 2) {
        int s0 = sorted_src[e], s1 = sorted_src[e + 1];
        float2 v0 = *(const float2*)(x + (size_t)s0 * D + c);
        float2 v1 = *(const float2*)(x + (size_t)s1 * D + c);
        acc.x += v0.x + v1.x;
        acc.y += v0.y + v1.y;
    }
    if (e < end) {
        int s = sorted_src[e];
        float2 v = *(const float2*)(x + (size_t)s * D + c);
        acc.x += v.x; acc.y += v.y;
    }
    *(float2*)(agg + (size_t)wave * D + c) = acc;
}

// In place: data[n][o] = relu(sum_k data[n][k] * Wt[k][o]) + x[n][o]
__global__ void __launch_bounds__(256)
gemm_relu_res(float* data,                      // agg in, out out (aliases!)
              const float* __restrict__ Wt,
              const float* __restrict__ x) {
    const int tx = threadIdx.x & 31;
    const int ty = threadIdx.x >> 5;
    const int o4 = tx << 2;
    const int n_base = blockIdx.x * 32 + ty * 4;

    float4 acc[4];
    acc[0] = acc[1] = acc[2] = acc[3] = make_float4(0.f, 0.f, 0.f, 0.f);

    const bool ok[4] = { n_base + 0 < N_NODES, n_base + 1 < N_NODES,
                         n_base + 2 < N_NODES, n_base + 3 < N_NODES };

    for (int k = 0; k < D; k += 4) {
        float4 w0 = *(const float4*)(Wt + (k + 0) * D + o4);
        float4 w1 = *(const float4*)(Wt + (k + 1) * D + o4);
        float4 w2 = *(const float4*)(Wt + (k + 2) * D + o4);
        float4 w3 = *(const float4*)(Wt + (k + 3) * D + o4);
#pragma unroll
        for (int i = 0; i < 4; ++i) {
            if (!ok[i]) continue;
            float4 a = *(const float4*)(data + (size_t)(n_base + i) * D + k);
            acc[i].x += a.x * w0.x + a.y * w1.x + a.z * w2.x + a.w * w3.x;
            acc[i].y += a.x * w0.y + a.y * w1.y + a.z * w2.y + a.w * w3.y;
            acc[i].z += a.x * w0.z + a.y * w1.z + a.z * w2.z + a.w * w3.z;
            acc[i].w += a.x * w0.w + a.y * w1.w + a.z * w2.w + a.w * w3.w;
        }
    }

#pragma unroll
    for (int i = 0; i < 4; ++i) {
        if (!ok[i]) continue;
        float4 xi = *(const float4*)(x + (size_t)(n_base + i) * D + o4);
        float4 r;
        r.x = fmaxf(acc[i].x, 0.f) + xi.x;
        r.y = fmaxf(acc[i].y, 0.f) + xi.y;
        r.z = fmaxf(acc[i].z, 0.f) + xi.z;
        r.w = fmaxf(acc[i].w, 0.f) + xi.w;
        *(float4*)(data + (size_t)(n_base + i) * D + o4) = r;
    }
}

extern "C" void kernel_launch(void* const* d_in, const int* in_sizes, int n_in,
                              void* d_out, int out_size, void* d_ws, size_t ws_size,
                              hipStream_t stream) {
    const float* x   = (const float*)d_in[0];
    const int*   src = (const int*)d_in[1];   // harness passes integers as int32
    const int*   dst = (const int*)d_in[2];
    const float* W   = (const float*)d_in[3];
    float* out = (float*)d_out;

    char* ws = (char*)d_ws;
    float* Wt         = (float*)ws;                      ws += (size_t)D * D * 4;
    int*   cnt        = (int*)ws;                        ws += (size_t)N_NODES * 4;
    int*   off        = (int*)ws;                        ws += (size_t)(N_NODES + 1) * 4;
    int*   cursor     = (int*)ws;                        ws += (size_t)N_NODES * 4;
    int*   sorted_src = (int*)ws;

    init_ws<<<(N_NODES + 255) / 256, 256, 0, stream>>>(cnt, cursor, W, Wt);
    histogram<<<(N_EDGES + 255) / 256, 256, 0, stream>>>(dst, cnt);
    scan_counts<<<1, SCAN_THREADS, 0, stream>>>(cnt, off);
    build_sorted<<<(N_EDGES + 255) / 256, 256, 0, stream>>>(src, dst, off, cursor, sorted_src);

    long long n_gather = (long long)N_NODES * 64;
    gather_sum<<<(int)((n_gather + 255) / 256), 256, 0, stream>>>(x, sorted_src, off, out);

    gemm_relu_res<<<(N_NODES + 31) / 32, 256, 0, stream>>>(out, Wt, x);
}

// Round 4
// 288.172 us; speedup vs baseline: 5.1534x; 1.2691x over previous
//
#include <hip/hip_runtime.h>
#include <hip/hip_bf16.h>

#define N_NODES 50000
#define N_EDGES 800000
#define D 128

#define SCAN_NBLOCKS ((N_NODES + 255) / 256)   // 196

// ---------------------------------------------------------------------------
// ws layout (all 4-byte elements, ~3.9 MB total):
//   Wt         : D*D floats          (64 KB)
//   cnt        : N_NODES ints
//   off        : N_NODES+1 ints
//   cursor     : N_NODES ints
//   blockoff   : SCAN_NBLOCKS ints   (196)
//   sorted_src : N_EDGES ints        (3.2 MB)
// d_out doubles as agg accumulator (gather-sum writes it, GEMM transforms
// it in place).
// ---------------------------------------------------------------------------

__global__ void init_ws(int* __restrict__ cnt, int* __restrict__ cursor,
                        const float* __restrict__ W, float* __restrict__ Wt) {
    int i = blockIdx.x * 256 + threadIdx.x;
    if (i < N_NODES) { cnt[i] = 0; cursor[i] = 0; }
    if (i < D * D)   Wt[i] = W[(i & 127) * D + (i >> 7)];   // Wt[k][o] = W[o][k]
}

__global__ void histogram(const int* __restrict__ dst, int* __restrict__ cnt) {
    int e = blockIdx.x * 256 + threadIdx.x;
    if (e >= N_EDGES) return;
    atomicAdd(&cnt[dst[e]], 1);
}

// Phase A: per-block reduce (coalesced), 196 blocks x 256 threads.
__global__ void __launch_bounds__(256)
scan_reduce(const int* __restrict__ cnt, int* __restrict__ blocksum) {
    int i = blockIdx.x * 256 + threadIdx.x;
    int v = (i < N_NODES) ? cnt[i] : 0;
#pragma unroll
    for (int o = 32; o; o >>= 1) v += __shfl_down(v, o, 64);
    __shared__ int ws_[4];
    if ((threadIdx.x & 63) == 0) ws_[threadIdx.x >> 6] = v;
    __syncthreads();
    if (threadIdx.x == 0)
        blocksum[blockIdx.x] = ws_[0] + ws_[1] + ws_[2] + ws_[3];
}

// Phase B: single tiny block scans the 196 block sums (exclusive),
// writes off[N_NODES] = grand total.
__global__ void __launch_bounds__(256)
scan_partials(const int* __restrict__ blocksum, int* __restrict__ blockoff,
              int* __restrict__ off) {
    __shared__ int sh[256];
    int t = threadIdx.x;
    int v = (t < SCAN_NBLOCKS) ? blocksum[t] : 0;
    sh[t] = v;
    __syncthreads();
    for (int o = 1; o < 256; o <<= 1) {
        int n = (t >= o) ? sh[t - o] : 0;
        __syncthreads();
        sh[t] += n;
        __syncthreads();
    }
    if (t < SCAN_NBLOCKS) blockoff[t] = sh[t] - v;      // exclusive
    if (t == SCAN_NBLOCKS - 1) off[N_NODES] = sh[t];    // total
}

// Phase C: per-block exclusive scan + block offset, coalesced.
__global__ void __launch_bounds__(256)
scan_final(const int* __restrict__ cnt, const int* __restrict__ blockoff,
           int* __restrict__ off) {
    int i = blockIdx.x * 256 + threadIdx.x;
    int lane = threadIdx.x & 63;
    int w    = threadIdx.x >> 6;
    int v = (i < N_NODES) ? cnt[i] : 0;
    int incl = v;
#pragma unroll
    for (int o = 1; o < 64; o <<= 1) {
        int n = __shfl_up(incl, o, 64);
        if (lane >= o) incl += n;
    }
    __shared__ int wsum[4];
    if (lane == 63) wsum[w] = incl;
    __syncthreads();
    int wofs = 0;
    for (int j = 0; j < w; ++j) wofs += wsum[j];
    if (i < N_NODES) off[i] = incl - v + wofs + blockoff[blockIdx.x];
}

__global__ void build_sorted(const int* __restrict__ src, const int* __restrict__ dst,
                             const int* __restrict__ off, int* __restrict__ cursor,
                             int* __restrict__ sorted_src) {
    int e = blockIdx.x * 256 + threadIdx.x;
    if (e >= N_EDGES) return;
    int d = dst[e];
    int p = off[d] + atomicAdd(&cursor[d], 1);
    sorted_src[p] = src[e];
}

// One wave per node: 64 lanes x float2 covers the 128-float row.
__global__ void __launch_bounds__(256)
gather_sum(const float* __restrict__ x,
           const int* __restrict__ sorted_src,
           const int* __restrict__ off,
           float* __restrict__ agg) {
    int wave = (int)((blockIdx.x * 256 + threadIdx.x) >> 6);
    int lane = threadIdx.x & 63;
    if (wave >= N_NODES) return;
    int beg = off[wave], end = off[wave + 1];
    const int c = lane * 2;
    float2 acc = make_float2(0.f, 0.f);
    int e = beg;
    for (; e + 1 < end; e += 2) {
        int s0 = sorted_src[e], s1 = sorted_src[e + 1];
        float2 v0 = *(const float2*)(x + (size_t)s0 * D + c);
        float2 v1 = *(const float2*)(x + (size_t)s1 * D + c);
        acc.x += v0.x + v1.x;
        acc.y += v0.y + v1.y;
    }
    if (e < end) {
        int s = sorted_src[e];
        float2 v = *(const float2*)(x + (size_t)s * D + c);
        acc.x += v.x; acc.y += v.y;
    }
    *(float2*)(agg + (size_t)wave * D + c) = acc;
}

// In place: data[n][o] = relu(sum_k data[n][k] * Wt[k][o]) + x[n][o]
__global__ void __launch_bounds__(256)
gemm_relu_res(float* data,                      // agg in, out out (aliases!)
              const float* __restrict__ Wt,
              const float* __restrict__ x) {
    const int tx = threadIdx.x & 31;
    const int ty = threadIdx.x >> 5;
    const int o4 = tx << 2;
    const int n_base = blockIdx.x * 32 + ty * 4;

    float4 acc[4];
    acc[0] = acc[1] = acc[2] = acc[3] = make_float4(0.f, 0.f, 0.f, 0.f);

    const bool ok[4] = { n_base + 0 < N_NODES, n_base + 1 < N_NODES,
                         n_base + 2 < N_NODES, n_base + 3 < N_NODES };

    for (int k = 0; k < D; k += 4) {
        float4 w0 = *(const float4*)(Wt + (k + 0) * D + o4);
        float4 w1 = *(const float4*)(Wt + (k + 1) * D + o4);
        float4 w2 = *(const float4*)(Wt + (k + 2) * D + o4);
        float4 w3 = *(const float4*)(Wt + (k + 3) * D + o4);
#pragma unroll
        for (int i = 0; i < 4; ++i) {
            if (!ok[i]) continue;
            float4 a = *(const float4*)(data + (size_t)(n_base + i) * D + k);
            acc[i].x += a.x * w0.x + a.y * w1.x + a.z * w2.x + a.w * w3.x;
            acc[i].y += a.x * w0.y + a.y * w1.y + a.z * w2.y + a.w * w3.y;
            acc[i].z += a.x * w0.z + a.y * w1.z + a.z * w2.z + a.w * w3.z;
            acc[i].w += a.x * w0.w + a.y * w1.w + a.z * w2.w + a.w * w3.w;
        }
    }

#pragma unroll
    for (int i = 0; i < 4; ++i) {
        if (!ok[i]) continue;
        float4 xi = *(const float4*)(x + (size_t)(n_base + i) * D + o4);
        float4 r;
        r.x = fmaxf(acc[i].x, 0.f) + xi.x;
        r.y = fmaxf(acc[i].y, 0.f) + xi.y;
        r.z = fmaxf(acc[i].z, 0.f) + xi.z;
        r.w = fmaxf(acc[i].w, 0.f) + xi.w;
        *(float4*)(data + (size_t)(n_base + i) * D + o4) = r;
    }
}

extern "C" void kernel_launch(void* const* d_in, const int* in_sizes, int n_in,
                              void* d_out, int out_size, void* d_ws, size_t ws_size,
                              hipStream_t stream) {
    const float* x   = (const float*)d_in[0];
    const int*   src = (const int*)d_in[1];   // harness passes integers as int32
    const int*   dst = (const int*)d_in[2];
    const float* W   = (const float*)d_in[3];
    float* out = (float*)d_out;

    char* ws = (char*)d_ws;
    float* Wt         = (float*)ws;   ws += (size_t)D * D * 4;
    int*   cnt        = (int*)ws;     ws += (size_t)N_NODES * 4;
    int*   off        = (int*)ws;     ws += (size_t)(N_NODES + 1) * 4;
    int*   cursor     = (int*)ws;     ws += (size_t)N_NODES * 4;
    int*   blockoff   = (int*)ws;     ws += (size_t)SCAN_NBLOCKS * 4;
    int*   sorted_src = (int*)ws;

    init_ws<<<(N_NODES + 255) / 256, 256, 0, stream>>>(cnt, cursor, W, Wt);
    histogram<<<(N_EDGES + 255) / 256, 256, 0, stream>>>(dst, cnt);
    scan_reduce<<<SCAN_NBLOCKS, 256, 0, stream>>>(cnt, blockoff /*as blocksum*/);
    // reuse cursor? no — blocksum lives in blockoff temporarily is WRONG
    // (we need both). Use a separate tiny kernel chain with distinct buffers:
    // blocksum stored in blockoff region is overwritten by scan_partials —
    // so pass a distinct buffer. We place blocksum in the tail of 'off'? No.
    // Simplest: blocksum = cursor region is also live later... use dedicated:
    scan_partials<<<1, 256, 0, stream>>>(blockoff /*blocksum in*/, blockoff /*excl out*/, off);
    scan_final<<<SCAN_NBLOCKS, 256, 0, stream>>>(cnt, blockoff, off);
    build_sorted<<<(N_EDGES + 255) / 256, 256, 0, stream>>>(src, dst, off, cursor, sorted_src);

    long long n_gather = (long long)N_NODES * 64;
    gather_sum<<<(int)((n_gather + 255) / 256), 256, 0, stream>>>(x, sorted_src, off, out);

    gemm_relu_res<<<(N_NODES + 31) / 32, 256, 0, stream>>>(out, Wt, x);
}